// Round 3
// baseline (205.535 us; speedup 1.0000x reference)
//
#include <hip/hip_runtime.h>

// ---------------------------------------------------------------------------
// MHLP predictor — fused f16 MFMA, occupancy + VALU-cut round.
// R19 (k_fused 97.4 us): Occ 24%, VALUBusy 56%, Mfma 12.6% -> latency-bound,
// LDS-capped at 5 blk/CU. This round:
//  * V never goes through LDS: transpose the 16x4x4 attention WEIGHTS (1 KB)
//    instead of the 32x64 V matrix; V stays in f32 regs in MFMA-output
//    layout which IS the ctx layout.  qkv[32][200] -> qk[32][136].
//  * 1 wave/block, per-block LDS 12320 B -> 13 blocks/CU = 13 waves (41%).
//  * arch residual kept in f32 regs (layout matches S5 needs exactly).
//  * scores via v_dot2_f32_f16 (fdot2) on packed f16 halves.
//  * b1 folded into W1 as virtual onehot row k=75 (KS=3 covers 96).
// LDS u16 map (per block = per wave, 6160 u16 = 12320 B):
//   SC   @0    (4352): h[16][136] -> qk[32][136] -> ctx[32][72]@0 +
//                      pooled[16][72]@2304
//   WATT @4352 (512):  f32 a-weights [16 s][4 h][4]
//   ARCH @4864 (1152): arch f16 [16][72] (A-frags for S3)
//   TARG @6016 (128), HWI @6144 (16)
// Frag layouts unchanged (m89/m91/m120-verified).
// Predict: k_fused ~60-68 us, Occ ~38%, VALUBusy ~75%, Mfma ~18%;
// absmax <= 9.77e-4 (V/residual more accurate).
// ---------------------------------------------------------------------------

using s8v = __attribute__((ext_vector_type(8))) short;
using h8  = __attribute__((ext_vector_type(8))) _Float16;
using h2v = __attribute__((ext_vector_type(2))) _Float16;
using f4  = __attribute__((ext_vector_type(4))) float;

#define BTOT 262144

// d_ws u16-unit layout (pre-swizzled f16 weight frags)
#define WF_W1   0        // 12288  (K=75(+bias row 75)->KS=3, NT=8)
#define WF_W2   12288    // 8192   (K=128->KS=4, NT=4)
#define WF_IP   20480    // 12288  (K=64->KS=2, NT=12)
#define WF_OP   32768    // 4096   (K=64->KS=2, NT=4)
#define WF_W3   36864    // 2048   (K=64->KS=2, NT=2)
#define WF_HWE  38912    // 256    (hw_embed f16 [4][64])

// per-block LDS offsets (u16 units)
#define OF_WATT 4352
#define OF_ARCH 4864
#define OF_TARG 6016
#define OF_HWI  6144
#define LDS_TOT 6160

__device__ __forceinline__ unsigned short f2h(float f) {
  _Float16 h = (_Float16)f;
  return __builtin_bit_cast(unsigned short, h);
}
__device__ __forceinline__ float h2f(unsigned short u) {
  return (float)__builtin_bit_cast(_Float16, u);
}

// swizzle W[N][Kreal] row-major f32 -> B-frag f16 layout; optional bias row
// at k == Kreal (folded-bias trick).
__device__ __forceinline__ void swz(const float* __restrict__ W,
                                    const float* __restrict__ bias,
                                    unsigned short* __restrict__ dst,
                                    int Kreal, int KS, int NT, int t, int stride) {
  const int total = KS * NT * 512;
  for (int i = t; i < total; i += stride) {
    const int j = i & 7, ln = (i >> 3) & 63, fr = i >> 9;
    const int nt = fr % NT, ks = fr / NT;
    const int n = nt * 16 + (ln & 15);
    const int k = ks * 32 + (ln >> 4) * 8 + j;
    float v = 0.f;
    if (k < Kreal) v = W[n * Kreal + k];
    else if (bias && k == Kreal) v = bias[n];
    dst[i] = f2h(v);
  }
}

__global__ void k_pre(const float* __restrict__ hwe,
                      const float* __restrict__ W1, const float* __restrict__ b1,
                      const float* __restrict__ W2,
                      const float* __restrict__ ipw, const float* __restrict__ opw,
                      const float* __restrict__ W3,
                      unsigned short* __restrict__ ws) {
  const int t = blockIdx.x * 256 + threadIdx.x;
  const int stride = gridDim.x * 256;
  swz(W1,  b1,      ws + WF_W1, 75, 3, 8, t, stride);
  swz(W2,  nullptr, ws + WF_W2, 128, 4, 4, t, stride);
  swz(ipw, nullptr, ws + WF_IP, 64, 2, 12, t, stride);
  swz(opw, nullptr, ws + WF_OP, 64, 2, 4, t, stride);
  swz(W3,  nullptr, ws + WF_W3, 64, 2, 2, t, stride);
  for (int i = t; i < 256; i += stride) ws[WF_HWE + i] = f2h(hwe[i]);
}

// ======================= fused: encoder + attention + head =================
__global__ __launch_bounds__(64, 3) void k_fused(
    const int* __restrict__ g_hw,
    const int* __restrict__ g_op, const int* __restrict__ g_wd,
    const float* __restrict__ g_hwe,
    const float* __restrict__ g_b2,
    const float* __restrict__ g_ln1g, const float* __restrict__ g_ln1b,
    const float* __restrict__ g_ipb, const float* __restrict__ g_opb,
    const float* __restrict__ g_ln2g, const float* __restrict__ g_ln2b,
    const float* __restrict__ g_b3,  const float* __restrict__ g_W4,
    const float* __restrict__ g_b4,
    const unsigned short* __restrict__ wsf,   // d_ws base (u16)
    float* __restrict__ g_out) {
  __shared__ __align__(16) unsigned short sm[LDS_TOT];
  const int lane = threadIdx.x;               // 64 threads = 1 wave
  const int quad = lane >> 4, l15 = lane & 15;
  unsigned short* pw = sm;
  const int m0 = blockIdx.x * 16;             // 16384 blocks x 16 samples

  // ---- per-tile index staging (wave-coherent) ----
  if (lane < 16) {
    const int smp = m0 + lane;
    pw[OF_HWI + lane] = (unsigned short)g_hw[smp];
#pragma unroll
    for (int l = 0; l < 5; ++l) {
      const int c = 15 * l + g_op[smp * 5 + l] * 3 + g_wd[smp * 5 + l];
      pw[OF_TARG + lane * 8 + l] = (unsigned short)c;
    }
    pw[OF_TARG + lane * 8 + 5] = 0xFFFFu;
    pw[OF_TARG + lane * 8 + 6] = 0xFFFFu;
    pw[OF_TARG + lane * 8 + 7] = 0xFFFFu;
  }
  const s8v trow = *(const s8v*)(pw + OF_TARG + l15 * 8);

  // ---- one-hot A-frags (k==75 is the folded-bias row, always 1) ----
  h8 aoh[3];
#pragma unroll
  for (int ks = 0; ks < 3; ++ks) {
    s8v a;
#pragma unroll
    for (int j = 0; j < 8; ++j) {
      const int k = ks * 32 + quad * 8 + j;
      bool hit = (k == 75);
#pragma unroll
      for (int l = 0; l < 5; ++l)
        hit = hit || (k == (int)(unsigned short)trow[l]);
      a[j] = hit ? (short)0x3C00 : (short)0;   // f16 1.0
    }
    aoh[ks] = __builtin_bit_cast(h8, a);
  }

  // S1: h = relu(onehot @ [W1;b1]^T) -> pw[0..2176) stride 136 (f16)
#pragma unroll
  for (int nt = 0; nt < 8; ++nt) {
    f4 acc = {0.f, 0.f, 0.f, 0.f};
#pragma unroll
    for (int ks = 0; ks < 3; ++ks) {
      const h8 bf = *(const h8*)(wsf + WF_W1 + ((ks * 8 + nt) * 64 + lane) * 8);
      acc = __builtin_amdgcn_mfma_f32_16x16x32_f16(aoh[ks], bf, acc, 0, 0, 0);
    }
    const int col = nt * 16 + l15;
#pragma unroll
    for (int r = 0; r < 4; ++r) {
      float v = acc[r];
      v = v > 0.f ? v : 0.f;
      pw[(quad * 4 + r) * 136 + col] = f2h(v);
    }
  }

  // S2: arch = LN1(h @ W2^T + b2) -> arch f16 @OF_ARCH, residual f32 in regs
  h8 a2[4];
#pragma unroll
  for (int ks = 0; ks < 4; ++ks)
    a2[ks] = *(const h8*)(pw + l15 * 136 + ks * 32 + quad * 8);
  f4 acc2[4];
#pragma unroll
  for (int nt = 0; nt < 4; ++nt) {
    f4 acc = {0.f, 0.f, 0.f, 0.f};
#pragma unroll
    for (int ks = 0; ks < 4; ++ks) {
      const h8 bf = *(const h8*)(wsf + WF_W2 + ((ks * 4 + nt) * 64 + lane) * 8);
      acc = __builtin_amdgcn_mfma_f32_16x16x32_f16(a2[ks], bf, acc, 0, 0, 0);
    }
    acc2[nt] = acc;
  }
  float archres[4][4];   // LN1 output f32, layout (row=quad*4+r, col=nt*16+l15)
  {
    float val[4][4];
#pragma unroll
    for (int nt = 0; nt < 4; ++nt) {
      const float bias = g_b2[nt * 16 + l15];
#pragma unroll
      for (int r = 0; r < 4; ++r) val[nt][r] = acc2[nt][r] + bias;
    }
#pragma unroll
    for (int r = 0; r < 4; ++r) {
      float s = val[0][r] + val[1][r] + val[2][r] + val[3][r];
      float q = val[0][r] * val[0][r] + val[1][r] * val[1][r] +
                val[2][r] * val[2][r] + val[3][r] * val[3][r];
#pragma unroll
      for (int off = 1; off <= 8; off <<= 1) {
        s += __shfl_xor(s, off);
        q += __shfl_xor(q, off);
      }
      const float mean = s * (1.f / 64.f);
      const float var  = q * (1.f / 64.f) - mean * mean;
      const float rstd = rsqrtf(var + 1e-5f);
#pragma unroll
      for (int nt = 0; nt < 4; ++nt) {
        const int col = nt * 16 + l15;
        const float gg = g_ln1g[col], bb = g_ln1b[col];
        const float xn = (val[nt][r] - mean) * rstd * gg + bb;
        archres[nt][r] = xn;
        pw[OF_ARCH + (quad * 4 + r) * 72 + col] = f2h(xn);
      }
    }
  }

  // S3: qkv = [hw_emb; arch] @ in_proj^T + ipb
  //   q,k (nt<8)  -> LDS qk[32][136] f16 (h region dead)
  //   v  (nt>=8)  -> f32 regs vreg[tok][nt-8][r]
  const int hwrow = (int)pw[OF_HWI + l15];
  h8 at0[2], at1[2];
#pragma unroll
  for (int ks = 0; ks < 2; ++ks) {
    at0[ks] = *(const h8*)(wsf + WF_HWE + hwrow * 64 + ks * 32 + quad * 8);
    at1[ks] = *(const h8*)(pw + OF_ARCH + l15 * 72 + ks * 32 + quad * 8);
  }
  float vreg[2][4][4];
#pragma unroll
  for (int nt = 0; nt < 12; ++nt) {
    const h8 bf0 = *(const h8*)(wsf + WF_IP + ((0 * 12 + nt) * 64 + lane) * 8);
    const h8 bf1 = *(const h8*)(wsf + WF_IP + ((1 * 12 + nt) * 64 + lane) * 8);
    f4 a0 = {0.f, 0.f, 0.f, 0.f}, a1 = {0.f, 0.f, 0.f, 0.f};
    a0 = __builtin_amdgcn_mfma_f32_16x16x32_f16(at0[0], bf0, a0, 0, 0, 0);
    a0 = __builtin_amdgcn_mfma_f32_16x16x32_f16(at0[1], bf1, a0, 0, 0, 0);
    a1 = __builtin_amdgcn_mfma_f32_16x16x32_f16(at1[0], bf0, a1, 0, 0, 0);
    a1 = __builtin_amdgcn_mfma_f32_16x16x32_f16(at1[1], bf1, a1, 0, 0, 0);
    const int col = nt * 16 + l15;
    const float bias = g_ipb[col];
    if (nt < 8) {
#pragma unroll
      for (int r = 0; r < 4; ++r) {
        pw[(quad * 4 + r) * 136 + col]      = f2h(a0[r] + bias);
        pw[(16 + quad * 4 + r) * 136 + col] = f2h(a1[r] + bias);
      }
    } else {
#pragma unroll
      for (int r = 0; r < 4; ++r) {
        vreg[0][nt - 8][r] = a0[r] + bias;
        vreg[1][nt - 8][r] = a1[r] + bias;
      }
    }
  }

  // S4a: scores + softmax per (sample=l15, head=quad); weights -> WATT
  {
    h8 qh[2][2], kh[2][2];
#pragma unroll
    for (int tt = 0; tt < 2; ++tt) {
      const unsigned short* base = pw + (tt * 16 + l15) * 136;
#pragma unroll
      for (int c = 0; c < 2; ++c) {
        qh[tt][c] = *(const h8*)(base + quad * 16 + c * 8);
        kh[tt][c] = *(const h8*)(base + 64 + quad * 16 + c * 8);
      }
    }
    float s2[2][2] = {{0.f, 0.f}, {0.f, 0.f}};
#pragma unroll
    for (int qt = 0; qt < 2; ++qt)
#pragma unroll
      for (int kt = 0; kt < 2; ++kt)
#pragma unroll
        for (int c = 0; c < 2; ++c) {
          const f4 qf = __builtin_bit_cast(f4, qh[qt][c]);
          const f4 kf = __builtin_bit_cast(f4, kh[kt][c]);
#pragma unroll
          for (int u = 0; u < 4; ++u) {
            const h2v qa = __builtin_bit_cast(h2v, qf[u]);
            const h2v ka = __builtin_bit_cast(h2v, kf[u]);
            s2[qt][kt] = __builtin_amdgcn_fdot2(qa, ka, s2[qt][kt], false);
          }
        }
    const float s00 = s2[0][0] * 0.25f, s01 = s2[0][1] * 0.25f;
    const float s10 = s2[1][0] * 0.25f, s11 = s2[1][1] * 0.25f;
    const float mA = fmaxf(s00, s01);
    const float e0 = __expf(s00 - mA), e1 = __expf(s01 - mA);
    const float iA = 1.f / (e0 + e1);
    const float mB = fmaxf(s10, s11);
    const float f0 = __expf(s10 - mB), f1 = __expf(s11 - mB);
    const float iB = 1.f / (f0 + f1);
    f4 w = {e0 * iA, e1 * iA, f0 * iB, f1 * iB};   // a00,a01,a10,a11
    ((f4*)(sm + OF_WATT))[l15 * 4 + quad] = w;
  }

  // S4b: ctx from in-reg V + transposed weights -> ctx[32][72] f16 @0
#pragma unroll
  for (int nt2 = 0; nt2 < 4; ++nt2)
#pragma unroll
    for (int r = 0; r < 4; ++r) {
      const f4 w = ((const f4*)(sm + OF_WATT))[(quad * 4 + r) * 4 + nt2];
      const float c0 = w[0] * vreg[0][nt2][r] + w[1] * vreg[1][nt2][r];
      const float c1 = w[2] * vreg[0][nt2][r] + w[3] * vreg[1][nt2][r];
      const int col = nt2 * 16 + l15;
      pw[(quad * 4 + r) * 72 + col]      = f2h(c0);
      pw[(16 + quad * 4 + r) * 72 + col] = f2h(c1);
    }

  // S5: out_proj + residual + LN2 + mean-pool -> pooled[16][72]@2304
  h8 ca[2][2];
#pragma unroll
  for (int mt = 0; mt < 2; ++mt)
#pragma unroll
    for (int ks = 0; ks < 2; ++ks)
      ca[mt][ks] = *(const h8*)(pw + (mt * 16 + l15) * 72 + ks * 32 + quad * 8);
  f4 oacc[2][4];
#pragma unroll
  for (int nt = 0; nt < 4; ++nt) {
    const h8 bf0 = *(const h8*)(wsf + WF_OP + ((0 * 4 + nt) * 64 + lane) * 8);
    const h8 bf1 = *(const h8*)(wsf + WF_OP + ((1 * 4 + nt) * 64 + lane) * 8);
#pragma unroll
    for (int mt = 0; mt < 2; ++mt) {
      f4 acc = {0.f, 0.f, 0.f, 0.f};
      acc = __builtin_amdgcn_mfma_f32_16x16x32_f16(ca[mt][0], bf0, acc, 0, 0, 0);
      acc = __builtin_amdgcn_mfma_f32_16x16x32_f16(ca[mt][1], bf1, acc, 0, 0, 0);
      oacc[mt][nt] = acc;
    }
  }
  float pool[4][4];
#pragma unroll
  for (int mt = 0; mt < 2; ++mt) {
    float val[4][4];
#pragma unroll
    for (int nt = 0; nt < 4; ++nt) {
      const int col = nt * 16 + l15;
      const float bias = g_opb[col];
#pragma unroll
      for (int r = 0; r < 4; ++r) {
        float res;
        if (mt == 0) {
          const int hr = (int)pw[OF_HWI + quad * 4 + r];
          res = g_hwe[hr * 64 + col];
        } else {
          res = archres[nt][r];
        }
        val[nt][r] = oacc[mt][nt][r] + bias + res;
      }
    }
#pragma unroll
    for (int r = 0; r < 4; ++r) {
      float s = val[0][r] + val[1][r] + val[2][r] + val[3][r];
      float q = val[0][r] * val[0][r] + val[1][r] * val[1][r] +
                val[2][r] * val[2][r] + val[3][r] * val[3][r];
#pragma unroll
      for (int off = 1; off <= 8; off <<= 1) {
        s += __shfl_xor(s, off);
        q += __shfl_xor(q, off);
      }
      const float mean = s * (1.f / 64.f);
      const float var  = q * (1.f / 64.f) - mean * mean;
      const float rstd = rsqrtf(var + 1e-5f);
#pragma unroll
      for (int nt = 0; nt < 4; ++nt) {
        const int col = nt * 16 + l15;
        const float gg = g_ln2g[col], bb = g_ln2b[col];
        const float xn = (val[nt][r] - mean) * rstd * gg + bb;
        if (mt == 0) pool[nt][r] = 0.5f * xn;
        else         pool[nt][r] += 0.5f * xn;
      }
    }
  }
#pragma unroll
  for (int nt = 0; nt < 4; ++nt)
#pragma unroll
    for (int r = 0; r < 4; ++r)
      pw[2304 + (quad * 4 + r) * 72 + nt * 16 + l15] = f2h(pool[nt][r]);

  // S6: head
  h8 pa[2];
#pragma unroll
  for (int ks = 0; ks < 2; ++ks)
    pa[ks] = *(const h8*)(pw + 2304 + l15 * 72 + ks * 32 + quad * 8);
  float part[4] = {0.f, 0.f, 0.f, 0.f};
#pragma unroll
  for (int nt = 0; nt < 2; ++nt) {
    const h8 bf0 = *(const h8*)(wsf + WF_W3 + ((0 * 2 + nt) * 64 + lane) * 8);
    const h8 bf1 = *(const h8*)(wsf + WF_W3 + ((1 * 2 + nt) * 64 + lane) * 8);
    f4 acc = {0.f, 0.f, 0.f, 0.f};
    acc = __builtin_amdgcn_mfma_f32_16x16x32_f16(pa[0], bf0, acc, 0, 0, 0);
    acc = __builtin_amdgcn_mfma_f32_16x16x32_f16(pa[1], bf1, acc, 0, 0, 0);
    const int col = nt * 16 + l15;
    const float bias = g_b3[col];
    const float w4v  = g_W4[col];
#pragma unroll
    for (int r = 0; r < 4; ++r) {
      float y = acc[r] + bias;
      y = y > 0.f ? y : 0.f;
      part[r] += y * w4v;
    }
  }
#pragma unroll
  for (int off = 1; off <= 8; off <<= 1)
#pragma unroll
    for (int r = 0; r < 4; ++r)
      part[r] += __shfl_xor(part[r], off);
  const float b4v = g_b4[0];
  if (l15 == 0) {
#pragma unroll
    for (int r = 0; r < 4; ++r)
      g_out[m0 + quad * 4 + r] = part[r] + b4v;
  }
}

extern "C" void kernel_launch(void* const* d_in, const int* in_sizes, int n_in,
                              void* d_out, int out_size, void* d_ws, size_t ws_size,
                              hipStream_t stream) {
  (void)in_sizes; (void)n_in; (void)out_size; (void)ws_size;
  unsigned short* ws = (unsigned short*)d_ws;

  k_pre<<<64, 256, 0, stream>>>(
      (const float*)d_in[3], (const float*)d_in[4], (const float*)d_in[5],
      (const float*)d_in[6], (const float*)d_in[10], (const float*)d_in[12],
      (const float*)d_in[16], ws);

  k_fused<<<16384, 64, 0, stream>>>(
      (const int*)d_in[0],
      (const int*)d_in[1], (const int*)d_in[2],
      (const float*)d_in[3],
      (const float*)d_in[7],
      (const float*)d_in[8], (const float*)d_in[9],
      (const float*)d_in[11], (const float*)d_in[13],
      (const float*)d_in[14], (const float*)d_in[15],
      (const float*)d_in[17], (const float*)d_in[18],
      (const float*)d_in[19],
      ws, (float*)d_out);
}

// Round 4
// 175.971 us; speedup vs baseline: 1.1680x; 1.1680x over previous
//
#include <hip/hip_runtime.h>

// ---------------------------------------------------------------------------
// MHLP predictor — fused f16 MFMA, in-register attention round.
// R20 post-mortem (129.7 us, regression): 1-wave blocks made the compiler
// target 8 waves/SIMD -> VGPR 52 -> no load ILP; WATT f4 transpose was a
// 16-way bank conflict; 16K blocks doubled prologue cost.
// This round: attention fully in-register.
//   * S3 restructured PER HEAD: q,k,v MFMAs computed & consumed together.
//     MFMA C-layout col=l15 is feat-within-head, row=quad*4+r is sample ->
//     score diff d=q·(k1-k0)/4 reduces over l15 via shfl_xor(1,2,4,8);
//     after reduce every lane holds weights for exactly the (sample,head)
//     its in-register V covers -> ctx = a·v lane-local. No qk LDS, no WATT.
//   * targ/hwi staging replaced by ds_bpermute broadcasts (6 shfls).
//   * all bias vectors (~41 scalars) hoisted to one burst at kernel top.
//   * LDS 9216 B/wave: ctx/h overlay[2304] pool[1152] arch[1152] u16.
//     256-thr 4-wave blocks = 36864 B -> 4 blk/CU = 16 waves/CU (50%).
// Predict: k_fused ~55-70 us, Occ ~45%, VALU ~65-75%, conflicts <1.5M,
// absmax <= 1e-3 (q,k never round-trip f16). Total ~130-150.
// ---------------------------------------------------------------------------

using s8v = __attribute__((ext_vector_type(8))) short;
using h8  = __attribute__((ext_vector_type(8))) _Float16;
using f4  = __attribute__((ext_vector_type(4))) float;

#define BTOT 262144

// d_ws u16-unit layout (pre-swizzled f16 weight frags)
#define WF_W1   0        // 12288  (K=75(+bias row 75)->KS=3, NT=8)
#define WF_W2   12288    // 8192   (K=128->KS=4, NT=4)
#define WF_IP   20480    // 12288  (K=64->KS=2, NT=12)
#define WF_OP   32768    // 4096   (K=64->KS=2, NT=4)
#define WF_W3   36864    // 2048   (K=64->KS=2, NT=2)
#define WF_HWE  38912    // 256    (hw_embed f16 [4][64])

// per-wave LDS offsets (u16 units)
#define OF_POOL 2304
#define OF_ARCH 3456
#define PWS     4608     // 9216 B per wave

__device__ __forceinline__ unsigned short f2h(float f) {
  _Float16 h = (_Float16)f;
  return __builtin_bit_cast(unsigned short, h);
}

// swizzle W[N][Kreal] row-major f32 -> B-frag f16 layout; optional bias row
// at k == Kreal (folded-bias trick).
__device__ __forceinline__ void swz(const float* __restrict__ W,
                                    const float* __restrict__ bias,
                                    unsigned short* __restrict__ dst,
                                    int Kreal, int KS, int NT, int t, int stride) {
  const int total = KS * NT * 512;
  for (int i = t; i < total; i += stride) {
    const int j = i & 7, ln = (i >> 3) & 63, fr = i >> 9;
    const int nt = fr % NT, ks = fr / NT;
    const int n = nt * 16 + (ln & 15);
    const int k = ks * 32 + (ln >> 4) * 8 + j;
    float v = 0.f;
    if (k < Kreal) v = W[n * Kreal + k];
    else if (bias && k == Kreal) v = bias[n];
    dst[i] = f2h(v);
  }
}

__global__ void k_pre(const float* __restrict__ hwe,
                      const float* __restrict__ W1, const float* __restrict__ b1,
                      const float* __restrict__ W2,
                      const float* __restrict__ ipw, const float* __restrict__ opw,
                      const float* __restrict__ W3,
                      unsigned short* __restrict__ ws) {
  const int t = blockIdx.x * 256 + threadIdx.x;
  const int stride = gridDim.x * 256;
  swz(W1,  b1,      ws + WF_W1, 75, 3, 8, t, stride);
  swz(W2,  nullptr, ws + WF_W2, 128, 4, 4, t, stride);
  swz(ipw, nullptr, ws + WF_IP, 64, 2, 12, t, stride);
  swz(opw, nullptr, ws + WF_OP, 64, 2, 4, t, stride);
  swz(W3,  nullptr, ws + WF_W3, 64, 2, 2, t, stride);
  for (int i = t; i < 256; i += stride) ws[WF_HWE + i] = f2h(hwe[i]);
}

// ======================= fused: encoder + attention + head =================
__global__ __launch_bounds__(256, 4) void k_fused(
    const int* __restrict__ g_hw,
    const int* __restrict__ g_op, const int* __restrict__ g_wd,
    const float* __restrict__ g_hwe,
    const float* __restrict__ g_b2,
    const float* __restrict__ g_ln1g, const float* __restrict__ g_ln1b,
    const float* __restrict__ g_ipb, const float* __restrict__ g_opb,
    const float* __restrict__ g_ln2g, const float* __restrict__ g_ln2b,
    const float* __restrict__ g_b3,  const float* __restrict__ g_W4,
    const float* __restrict__ g_b4,
    const unsigned short* __restrict__ wsf,   // d_ws base (u16)
    float* __restrict__ g_out) {
  __shared__ __align__(16) unsigned short sm[4 * PWS];
  const int tid = threadIdx.x;
  const int wave = tid >> 6, lane = tid & 63;
  const int quad = lane >> 4, l15 = lane & 15;
  unsigned short* pw = sm + wave * PWS;
  const int m0 = (blockIdx.x * 4 + wave) * 16;   // 4096 blocks x 4 waves

  // ---- index loads (lanes 0..15) + in-wave broadcasts ----
  int hwv = 0, c0 = 0, c1 = 0, c2 = 0, c3 = 0, c4 = 0;
  if (lane < 16) {
    const int smp = m0 + lane;
    hwv = g_hw[smp];
    c0 =      g_op[smp * 5 + 0] * 3 + g_wd[smp * 5 + 0];
    c1 = 15 + g_op[smp * 5 + 1] * 3 + g_wd[smp * 5 + 1];
    c2 = 30 + g_op[smp * 5 + 2] * 3 + g_wd[smp * 5 + 2];
    c3 = 45 + g_op[smp * 5 + 3] * 3 + g_wd[smp * 5 + 3];
    c4 = 60 + g_op[smp * 5 + 4] * 3 + g_wd[smp * 5 + 4];
  }
  const int t0 = __shfl(c0, l15), t1 = __shfl(c1, l15), t2 = __shfl(c2, l15);
  const int t3 = __shfl(c3, l15), t4 = __shfl(c4, l15);
  const int hwrow = __shfl(hwv, l15);

  // ---- hoisted bias/param loads (one burst; L1-resident after 1st block) --
  float b2v[4], l1gv[4], l1bv[4], opbv[4], l2gv[4], l2bv[4];
#pragma unroll
  for (int nt = 0; nt < 4; ++nt) {
    const int col = nt * 16 + l15;
    b2v[nt] = g_b2[col];  l1gv[nt] = g_ln1g[col]; l1bv[nt] = g_ln1b[col];
    opbv[nt] = g_opb[col]; l2gv[nt] = g_ln2g[col]; l2bv[nt] = g_ln2b[col];
  }
  float ipbv[12];
#pragma unroll
  for (int nt = 0; nt < 12; ++nt) ipbv[nt] = g_ipb[nt * 16 + l15];
  float b3v[2], w4vv[2];
#pragma unroll
  for (int nt = 0; nt < 2; ++nt) {
    b3v[nt] = g_b3[nt * 16 + l15];
    w4vv[nt] = g_W4[nt * 16 + l15];
  }
  const float b4v = g_b4[0];

  // ---- one-hot A-frags (k==75 is the folded-bias row, always 1) ----
  h8 aoh[3];
#pragma unroll
  for (int ks = 0; ks < 3; ++ks) {
    s8v a;
#pragma unroll
    for (int j = 0; j < 8; ++j) {
      const int k = ks * 32 + quad * 8 + j;
      const bool hit = (k == 75) || (k == t0) || (k == t1) || (k == t2) ||
                       (k == t3) || (k == t4);
      a[j] = hit ? (short)0x3C00 : (short)0;   // f16 1.0
    }
    aoh[ks] = __builtin_bit_cast(h8, a);
  }

  // S1: h = relu(onehot @ [W1;b1]^T) -> pw[0..2176) stride 136 (f16)
#pragma unroll
  for (int nt = 0; nt < 8; ++nt) {
    f4 acc = {0.f, 0.f, 0.f, 0.f};
#pragma unroll
    for (int ks = 0; ks < 3; ++ks) {
      const h8 bf = *(const h8*)(wsf + WF_W1 + ((ks * 8 + nt) * 64 + lane) * 8);
      acc = __builtin_amdgcn_mfma_f32_16x16x32_f16(aoh[ks], bf, acc, 0, 0, 0);
    }
    const int col = nt * 16 + l15;
#pragma unroll
    for (int r = 0; r < 4; ++r) {
      float v = acc[r];
      v = v > 0.f ? v : 0.f;
      pw[(quad * 4 + r) * 136 + col] = f2h(v);
    }
  }

  // S2: arch = LN1(h @ W2^T + b2) -> arch f16 @OF_ARCH, residual f32 in regs
  h8 a2[4];
#pragma unroll
  for (int ks = 0; ks < 4; ++ks)
    a2[ks] = *(const h8*)(pw + l15 * 136 + ks * 32 + quad * 8);
  float archres[4][4];   // LN1 out f32, layout (row=quad*4+r, col=nt*16+l15)
  {
    float val[4][4];
#pragma unroll
    for (int nt = 0; nt < 4; ++nt) {
      f4 acc = {0.f, 0.f, 0.f, 0.f};
#pragma unroll
      for (int ks = 0; ks < 4; ++ks) {
        const h8 bf = *(const h8*)(wsf + WF_W2 + ((ks * 4 + nt) * 64 + lane) * 8);
        acc = __builtin_amdgcn_mfma_f32_16x16x32_f16(a2[ks], bf, acc, 0, 0, 0);
      }
#pragma unroll
      for (int r = 0; r < 4; ++r) val[nt][r] = acc[r] + b2v[nt];
    }
#pragma unroll
    for (int r = 0; r < 4; ++r) {
      float s = val[0][r] + val[1][r] + val[2][r] + val[3][r];
      float q = val[0][r] * val[0][r] + val[1][r] * val[1][r] +
                val[2][r] * val[2][r] + val[3][r] * val[3][r];
#pragma unroll
      for (int off = 1; off <= 8; off <<= 1) {
        s += __shfl_xor(s, off);
        q += __shfl_xor(q, off);
      }
      const float mean = s * (1.f / 64.f);
      const float var  = q * (1.f / 64.f) - mean * mean;
      const float rstd = rsqrtf(var + 1e-5f);
#pragma unroll
      for (int nt = 0; nt < 4; ++nt) {
        const int col = nt * 16 + l15;
        const float xn = (val[nt][r] - mean) * rstd * l1gv[nt] + l1bv[nt];
        archres[nt][r] = xn;
        pw[OF_ARCH + (quad * 4 + r) * 72 + col] = f2h(xn);
      }
    }
  }

  // S3+S4 fused PER HEAD: qkv MFMAs -> in-register scores/softmax/ctx.
  // ctx[32][72] f16 overlays the h region @0 (h dead after a2 reads).
  h8 at0[2], at1[2];
#pragma unroll
  for (int ks = 0; ks < 2; ++ks) {
    at0[ks] = *(const h8*)(wsf + WF_HWE + hwrow * 64 + ks * 32 + quad * 8);
    at1[ks] = *(const h8*)(pw + OF_ARCH + l15 * 72 + ks * 32 + quad * 8);
  }
#pragma unroll
  for (int h = 0; h < 4; ++h) {
    f4 aq0 = {0.f,0.f,0.f,0.f}, aq1 = {0.f,0.f,0.f,0.f};
    f4 ak0 = {0.f,0.f,0.f,0.f}, ak1 = {0.f,0.f,0.f,0.f};
    f4 av0 = {0.f,0.f,0.f,0.f}, av1 = {0.f,0.f,0.f,0.f};
#pragma unroll
    for (int ks = 0; ks < 2; ++ks) {
      const h8 bq = *(const h8*)(wsf + WF_IP + ((ks * 12 + h    ) * 64 + lane) * 8);
      const h8 bk = *(const h8*)(wsf + WF_IP + ((ks * 12 + h + 4) * 64 + lane) * 8);
      const h8 bv = *(const h8*)(wsf + WF_IP + ((ks * 12 + h + 8) * 64 + lane) * 8);
      aq0 = __builtin_amdgcn_mfma_f32_16x16x32_f16(at0[ks], bq, aq0, 0, 0, 0);
      aq1 = __builtin_amdgcn_mfma_f32_16x16x32_f16(at1[ks], bq, aq1, 0, 0, 0);
      ak0 = __builtin_amdgcn_mfma_f32_16x16x32_f16(at0[ks], bk, ak0, 0, 0, 0);
      ak1 = __builtin_amdgcn_mfma_f32_16x16x32_f16(at1[ks], bk, ak1, 0, 0, 0);
      av0 = __builtin_amdgcn_mfma_f32_16x16x32_f16(at0[ks], bv, av0, 0, 0, 0);
      av1 = __builtin_amdgcn_mfma_f32_16x16x32_f16(at1[ks], bv, av1, 0, 0, 0);
    }
    // score diffs d[qt] = q[qt]·(k1-k0), reduced over feat=l15 within quad
    float d0[4], d1[4], v0[4], v1[4];
#pragma unroll
    for (int r = 0; r < 4; ++r) {
      const float dk = (ak1[r] + ipbv[h + 4]) - (ak0[r] + ipbv[h + 4]);
      d0[r] = (aq0[r] + ipbv[h]) * dk;
      d1[r] = (aq1[r] + ipbv[h]) * dk;
      v0[r] = av0[r] + ipbv[h + 8];
      v1[r] = av1[r] + ipbv[h + 8];
    }
#pragma unroll
    for (int off = 1; off <= 8; off <<= 1)
#pragma unroll
      for (int r = 0; r < 4; ++r) {
        d0[r] += __shfl_xor(d0[r], off);
        d1[r] += __shfl_xor(d1[r], off);
      }
    // softmax over 2 keys + ctx = a·v (all lane-local)
#pragma unroll
    for (int r = 0; r < 4; ++r) {
      const float dsc0 = d0[r] * 0.25f, dsc1 = d1[r] * 0.25f;
      const float g0 = fmaxf(dsc0, 0.f);
      const float e01 = __expf(dsc0 - g0), e00 = __expf(-g0);
      const float i0 = 1.f / (e00 + e01);
      const float g1 = fmaxf(dsc1, 0.f);
      const float e11 = __expf(dsc1 - g1), e10 = __expf(-g1);
      const float i1 = 1.f / (e10 + e11);
      const float ctx0 = (e00 * i0) * v0[r] + (e01 * i0) * v1[r];
      const float ctx1 = (e10 * i1) * v0[r] + (e11 * i1) * v1[r];
      const int col = h * 16 + l15;
      pw[(quad * 4 + r) * 72 + col]        = f2h(ctx0);
      pw[(16 + quad * 4 + r) * 72 + col]   = f2h(ctx1);
    }
  }

  // S5: out_proj + residual + LN2 + mean-pool -> pooled[16][72]@OF_POOL
  h8 ca[2][2];
#pragma unroll
  for (int mt = 0; mt < 2; ++mt)
#pragma unroll
    for (int ks = 0; ks < 2; ++ks)
      ca[mt][ks] = *(const h8*)(pw + (mt * 16 + l15) * 72 + ks * 32 + quad * 8);
  f4 oacc[2][4];
#pragma unroll
  for (int nt = 0; nt < 4; ++nt) {
    const h8 bf0 = *(const h8*)(wsf + WF_OP + ((0 * 4 + nt) * 64 + lane) * 8);
    const h8 bf1 = *(const h8*)(wsf + WF_OP + ((1 * 4 + nt) * 64 + lane) * 8);
#pragma unroll
    for (int mt = 0; mt < 2; ++mt) {
      f4 acc = {0.f, 0.f, 0.f, 0.f};
      acc = __builtin_amdgcn_mfma_f32_16x16x32_f16(ca[mt][0], bf0, acc, 0, 0, 0);
      acc = __builtin_amdgcn_mfma_f32_16x16x32_f16(ca[mt][1], bf1, acc, 0, 0, 0);
      oacc[mt][nt] = acc;
    }
  }
  float pool[4][4];
#pragma unroll
  for (int mt = 0; mt < 2; ++mt) {
    float val[4][4];
#pragma unroll
    for (int r = 0; r < 4; ++r) {
      if (mt == 0) {
        const int hr = __shfl(hwv, quad * 4 + r);
#pragma unroll
        for (int nt = 0; nt < 4; ++nt)
          val[nt][r] = oacc[0][nt][r] + opbv[nt] + g_hwe[hr * 64 + nt * 16 + l15];
      } else {
#pragma unroll
        for (int nt = 0; nt < 4; ++nt)
          val[nt][r] = oacc[1][nt][r] + opbv[nt] + archres[nt][r];
      }
    }
#pragma unroll
    for (int r = 0; r < 4; ++r) {
      float s = val[0][r] + val[1][r] + val[2][r] + val[3][r];
      float q = val[0][r] * val[0][r] + val[1][r] * val[1][r] +
                val[2][r] * val[2][r] + val[3][r] * val[3][r];
#pragma unroll
      for (int off = 1; off <= 8; off <<= 1) {
        s += __shfl_xor(s, off);
        q += __shfl_xor(q, off);
      }
      const float mean = s * (1.f / 64.f);
      const float var  = q * (1.f / 64.f) - mean * mean;
      const float rstd = rsqrtf(var + 1e-5f);
#pragma unroll
      for (int nt = 0; nt < 4; ++nt) {
        const float xn = (val[nt][r] - mean) * rstd * l2gv[nt] + l2bv[nt];
        if (mt == 0) pool[nt][r] = 0.5f * xn;
        else         pool[nt][r] += 0.5f * xn;
      }
    }
  }
#pragma unroll
  for (int nt = 0; nt < 4; ++nt)
#pragma unroll
    for (int r = 0; r < 4; ++r)
      pw[OF_POOL + (quad * 4 + r) * 72 + nt * 16 + l15] = f2h(pool[nt][r]);

  // S6: head
  h8 pa[2];
#pragma unroll
  for (int ks = 0; ks < 2; ++ks)
    pa[ks] = *(const h8*)(pw + OF_POOL + l15 * 72 + ks * 32 + quad * 8);
  float part[4] = {0.f, 0.f, 0.f, 0.f};
#pragma unroll
  for (int nt = 0; nt < 2; ++nt) {
    const h8 bf0 = *(const h8*)(wsf + WF_W3 + ((0 * 2 + nt) * 64 + lane) * 8);
    const h8 bf1 = *(const h8*)(wsf + WF_W3 + ((1 * 2 + nt) * 64 + lane) * 8);
    f4 acc = {0.f, 0.f, 0.f, 0.f};
    acc = __builtin_amdgcn_mfma_f32_16x16x32_f16(pa[0], bf0, acc, 0, 0, 0);
    acc = __builtin_amdgcn_mfma_f32_16x16x32_f16(pa[1], bf1, acc, 0, 0, 0);
#pragma unroll
    for (int r = 0; r < 4; ++r) {
      float y = acc[r] + b3v[nt];
      y = y > 0.f ? y : 0.f;
      part[r] += y * w4vv[nt];
    }
  }
#pragma unroll
  for (int off = 1; off <= 8; off <<= 1)
#pragma unroll
    for (int r = 0; r < 4; ++r)
      part[r] += __shfl_xor(part[r], off);
  if (l15 == 0) {
#pragma unroll
    for (int r = 0; r < 4; ++r)
      g_out[m0 + quad * 4 + r] = part[r] + b4v;
  }
}

extern "C" void kernel_launch(void* const* d_in, const int* in_sizes, int n_in,
                              void* d_out, int out_size, void* d_ws, size_t ws_size,
                              hipStream_t stream) {
  (void)in_sizes; (void)n_in; (void)out_size; (void)ws_size;
  unsigned short* ws = (unsigned short*)d_ws;

  k_pre<<<64, 256, 0, stream>>>(
      (const float*)d_in[3], (const float*)d_in[4], (const float*)d_in[5],
      (const float*)d_in[6], (const float*)d_in[10], (const float*)d_in[12],
      (const float*)d_in[16], ws);

  k_fused<<<4096, 256, 0, stream>>>(
      (const int*)d_in[0],
      (const int*)d_in[1], (const int*)d_in[2],
      (const float*)d_in[3],
      (const float*)d_in[7],
      (const float*)d_in[8], (const float*)d_in[9],
      (const float*)d_in[11], (const float*)d_in[13],
      (const float*)d_in[14], (const float*)d_in[15],
      (const float*)d_in[17], (const float*)d_in[18],
      (const float*)d_in[19],
      ws, (float*)d_out);
}